// Round 1
// baseline (1619.512 us; speedup 1.0000x reference)
//
#include <hip/hip_runtime.h>
#include <math.h>

#define NMESH 120
#define NKZ 61            // rfft half-spectrum along z
#define NTOT (120*120*120)
#define ALPHA_C 1.0

// ---- workspace layout (bytes) ----
// [0,24)        : 3 doubles: ek_acc, sq_acc, sq2_acc
// [64,115264)   : float2 T[120*120] twiddle table, T[z*120+k] = e^{-2pi i z k/120}
// [115264, +6912000)  : float mesh[120^3]
// [7027264, +7027200) : float2 C1[120*120*61]   layout [x][y][kz]
// [14054464,+7027200) : float2 C2[120*61*120]   layout [x][kz][ky]
#define ACC_OFF   0
#define TAB_OFF   64
#define MESH_OFF  115264
#define C1_OFF    7027264
#define C2_OFF    14054464
#define ZERO_BYTES 7027264   // zero accumulators + (table, harmless) + mesh

__device__ inline void inv3(const float* b, float* ib) {
    float a00=b[0],a01=b[1],a02=b[2],a10=b[3],a11=b[4],a12=b[5],a20=b[6],a21=b[7],a22=b[8];
    float c00 =  a11*a22 - a12*a21;
    float c01 = -(a10*a22 - a12*a20);
    float c02 =  a10*a21 - a11*a20;
    float c10 = -(a01*a22 - a02*a21);
    float c11 =  a00*a22 - a02*a20;
    float c12 = -(a00*a21 - a01*a20);
    float c20 =  a01*a12 - a02*a11;
    float c21 = -(a00*a12 - a02*a10);
    float c22 =  a00*a11 - a01*a10;
    float det = a00*c00 + a01*c01 + a02*c02;
    float inv = 1.0f/det;
    // inverse = adj/det, adj = cof^T : ib[i*3+j] = cof[j][i]*inv
    ib[0]=c00*inv; ib[1]=c10*inv; ib[2]=c20*inv;
    ib[3]=c01*inv; ib[4]=c11*inv; ib[5]=c21*inv;
    ib[6]=c02*inv; ib[7]=c12*inv; ib[8]=c22*inv;
}

__global__ void table_kernel(float2* __restrict__ T) {
    int idx = blockIdx.x*blockDim.x + threadIdx.x;
    if (idx >= 120*120) return;
    int z = idx/120, k = idx - z*120;
    int m = (z*k) % 120;                       // exact angle reduction
    double ang = (2.0*M_PI/120.0) * (double)m;
    T[idx] = make_float2((float)cos(ang), (float)(-sin(ang)));
}

__global__ void reduce_q_kernel(const float* __restrict__ q, double* __restrict__ acc, int n) {
    int i = blockIdx.x*blockDim.x + threadIdx.x;
    float v = 0.f, v2 = 0.f;
    if (i < n) { v = q[i]; v2 = v*v; }
    #pragma unroll
    for (int o=32;o>0;o>>=1) { v += __shfl_down(v,o,64); v2 += __shfl_down(v2,o,64); }
    __shared__ float s1[4], s2[4];
    int lane = threadIdx.x & 63, w = threadIdx.x >> 6;
    if (lane==0) { s1[w]=v; s2[w]=v2; }
    __syncthreads();
    if (threadIdx.x==0) {
        for (int j=1;j<4;j++) { v += s1[j]; v2 += s2[j]; }
        atomicAdd(&acc[1], (double)v);
        atomicAdd(&acc[2], (double)v2);
    }
}

__global__ void spread_kernel(const float* __restrict__ coords,
                              const float* __restrict__ box,
                              const float* __restrict__ charges,
                              float* __restrict__ mesh, int n) {
    int i = blockIdx.x*blockDim.x + threadIdx.x;
    if (i >= n) return;
    float ib[9]; inv3(box, ib);
    float c0 = coords[3*i], c1 = coords[3*i+1], c2 = coords[3*i+2];
    float q = charges[i];
    float w[3][6]; int g[3][6];
    #pragma unroll
    for (int d=0; d<3; ++d) {
        float frac = c0*ib[0+d] + c1*ib[3+d] + c2*ib[6+d];   // frac[d] = sum_m c[m]*inv[m][d]
        float pos = frac * 120.0f;
        float fi0 = floorf(pos);
        float x = pos - (fi0 + 0.5f);
        float df[6];
        #pragma unroll
        for (int k=0;k<6;++k) df[k] = x - ((float)k - 2.5f);
        w[d][0] = df[1]*df[2]*df[3]*df[4]*df[5] * (-1.0f/120.0f);
        w[d][1] = df[0]*df[2]*df[3]*df[4]*df[5] * ( 1.0f/24.0f);
        w[d][2] = df[0]*df[1]*df[3]*df[4]*df[5] * (-1.0f/12.0f);
        w[d][3] = df[0]*df[1]*df[2]*df[4]*df[5] * ( 1.0f/12.0f);
        w[d][4] = df[0]*df[1]*df[2]*df[3]*df[5] * (-1.0f/24.0f);
        w[d][5] = df[0]*df[1]*df[2]*df[3]*df[4] * ( 1.0f/120.0f);
        int i0 = (int)fi0;
        #pragma unroll
        for (int o=0;o<6;++o) g[d][o] = (i0 + o - 2 + 240) % 120;
    }
    #pragma unroll
    for (int a=0;a<6;++a) {
        int base_a = g[0][a]*14400;
        float wa = w[0][a]*q;
        #pragma unroll
        for (int b=0;b<6;++b) {
            int base_ab = base_a + g[1][b]*120;
            float wab = wa*w[1][b];
            #pragma unroll
            for (int c=0;c<6;++c)
                atomicAdd(&mesh[base_ab + g[2][c]], wab*w[2][c]);
        }
    }
}

// stage 1: rfft along z. one block per (x,y) line.
__global__ void fft_z_kernel(const float* __restrict__ mesh,
                             const float2* __restrict__ T,
                             float2* __restrict__ C1) {
    int line = blockIdx.x;                 // x*120+y
    __shared__ float lds[120];
    const float* src = mesh + line*120;
    for (int i = threadIdx.x; i < 120; i += 64) lds[i] = src[i];
    __syncthreads();
    int kz = threadIdx.x;
    if (kz < NKZ) {
        float re = 0.f, im = 0.f;
        for (int z=0; z<120; ++z) {
            float v = lds[z];
            float2 t = T[z*120 + kz];
            re = fmaf(v, t.x, re);
            im = fmaf(v, t.y, im);
        }
        C1[line*NKZ + kz] = make_float2(re, im);
    }
}

// stage 2: cfft along y. one block per (x,kz).
__global__ void fft_y_kernel(const float2* __restrict__ C1,
                             const float2* __restrict__ T,
                             float2* __restrict__ C2) {
    int x  = blockIdx.x / NKZ;
    int kz = blockIdx.x - x*NKZ;
    __shared__ float2 lds[120];
    for (int y = threadIdx.x; y < 120; y += 128) lds[y] = C1[(x*120 + y)*NKZ + kz];
    __syncthreads();
    int ky = threadIdx.x;
    if (ky < 120) {
        float re = 0.f, im = 0.f;
        for (int y=0; y<120; ++y) {
            float2 a = lds[y];
            float2 t = T[y*120 + ky];
            re = fmaf(a.x, t.x, fmaf(-a.y, t.y, re));
            im = fmaf(a.x, t.y, fmaf( a.y, t.x, im));
        }
        C2[(x*NKZ + kz)*120 + ky] = make_float2(re, im);   // layout [x][kz][ky], coalesced
    }
}

// stage 3: cfft along x, fused with energy reduction. one block per (ky,kz).
__global__ void fft_x_energy_kernel(const float2* __restrict__ C2,
                                    const float2* __restrict__ T,
                                    const float* __restrict__ box,
                                    double* __restrict__ acc) {
    int ky = blockIdx.x / NKZ;
    int kz = blockIdx.x - ky*NKZ;
    __shared__ float2 lds[120];
    for (int x = threadIdx.x; x < 120; x += 128) lds[x] = C2[(x*NKZ + kz)*120 + ky];
    __syncthreads();
    float contrib = 0.f;
    int kx = threadIdx.x;
    if (kx < 120) {
        float re = 0.f, im = 0.f;
        for (int x=0; x<120; ++x) {
            float2 a = lds[x];
            float2 t = T[x*120 + kx];
            re = fmaf(a.x, t.x, fmaf(-a.y, t.y, re));
            im = fmaf(a.x, t.y, fmaf( a.y, t.x, im));
        }
        if (!(kx==0 && ky==0 && kz==0)) {
            float mx = (kx < 60) ? (float)kx : (float)(kx - 120);
            float my = (ky < 60) ? (float)ky : (float)(ky - 120);
            float mz = (float)kz;
            float ib[9]; inv3(box, ib);
            const float TWOPI = 6.283185307179586f;
            // k[n] = 2pi * sum_m mvec[m] * inv_cell[n][m]
            float k0 = TWOPI*(mx*ib[0] + my*ib[1] + mz*ib[2]);
            float k1 = TWOPI*(mx*ib[3] + my*ib[4] + mz*ib[5]);
            float k2 = TWOPI*(mx*ib[6] + my*ib[7] + mz*ib[8]);
            float ksq = k0*k0 + k1*k1 + k2*k2;
            float G = 12.566370614359172f * __expf(-0.5f*(float)(ALPHA_C*ALPHA_C)*ksq) / ksq;
            float wgt = (kz==0 || kz==60) ? 1.0f : 2.0f;
            contrib = wgt * G * (re*re + im*im);
        }
    }
    // block reduce (128 threads = 2 waves)
    float v = contrib;
    #pragma unroll
    for (int o=32;o>0;o>>=1) v += __shfl_down(v,o,64);
    __shared__ float sm[2];
    int lane = threadIdx.x & 63, w = threadIdx.x >> 6;
    if (lane==0) sm[w] = v;
    __syncthreads();
    if (threadIdx.x==0) atomicAdd(&acc[0], (double)(v + sm[1]));
}

__global__ void finalize_kernel(const double* __restrict__ acc,
                                const float* __restrict__ box,
                                float* __restrict__ out) {
    double ek = acc[0], sq = acc[1], sq2 = acc[2];
    double a00=box[0],a01=box[1],a02=box[2],a10=box[3],a11=box[4],a12=box[5],a20=box[6],a21=box[7],a22=box[8];
    double det = a00*(a11*a22-a12*a21) - a01*(a10*a22-a12*a20) + a02*(a10*a21-a11*a20);
    double vol = fabs(det);
    double E = ek/(2.0*vol)
             - 0.5*sqrt(2.0/M_PI)/ALPHA_C * sq2
             - M_PI*ALPHA_C*ALPHA_C * sq*sq / vol;
    out[0] = (float)E;
}

extern "C" void kernel_launch(void* const* d_in, const int* in_sizes, int n_in,
                              void* d_out, int out_size, void* d_ws, size_t ws_size,
                              hipStream_t stream) {
    const float* coords  = (const float*)d_in[0];
    const float* box     = (const float*)d_in[1];
    const float* charges = (const float*)d_in[2];
    int n = in_sizes[0] / 3;

    char* ws = (char*)d_ws;
    double* acc  = (double*)(ws + ACC_OFF);
    float2* T    = (float2*)(ws + TAB_OFF);
    float*  mesh = (float*) (ws + MESH_OFF);
    float2* C1   = (float2*)(ws + C1_OFF);
    float2* C2   = (float2*)(ws + C2_OFF);

    hipMemsetAsync(d_ws, 0, ZERO_BYTES, stream);
    table_kernel<<<(14400+255)/256, 256, 0, stream>>>(T);
    reduce_q_kernel<<<(n+255)/256, 256, 0, stream>>>(charges, acc, n);
    spread_kernel<<<(n+255)/256, 256, 0, stream>>>(coords, box, charges, mesh, n);
    fft_z_kernel<<<120*120, 64, 0, stream>>>(mesh, T, C1);
    fft_y_kernel<<<120*NKZ, 128, 0, stream>>>(C1, T, C2);
    fft_x_energy_kernel<<<120*NKZ, 128, 0, stream>>>(C2, T, box, acc);
    finalize_kernel<<<1, 1, 0, stream>>>(acc, box, (float*)d_out);
}

// Round 2
// 725.365 us; speedup vs baseline: 2.2327x; 2.2327x over previous
//
#include <hip/hip_runtime.h>
#include <math.h>

#define NMESH 120
#define NKZ 61            // rfft half-spectrum along z
#define NTOT (120*120*120)
#define ALPHA_C 1.0

#define TILE 12           // mesh cells per tile per dim
#define NTPD 10           // tiles per dim
#define NTILE 1000
#define FP 17             // footprint per dim: TILE + 5
#define FPCELLS (FP*FP*FP)   // 4913

// ---- workspace layout (bytes) ----
// [0,24)        : 3 doubles: ek_acc, sq_acc, sq2_acc
// [64,115264)   : float2 T[120*120] twiddle table, T[z*120+k] = e^{-2pi i z k/120}
// [115264, +6912000)  : float mesh[120^3]
// [7027264, +7027200) : float2 C1  — ALSO (before fft_z) bin ints:
//                        counts @C1_OFF, offsets @C1_OFF+4096, cursor @C1_OFF+8192
// [14054464,+7027200) : float2 C2  — ALSO (before fft_y) sorted float4 atoms
#define ACC_OFF   0
#define TAB_OFF   64
#define MESH_OFF  115264
#define C1_OFF    7027264
#define C2_OFF    14054464
#define ZERO_BYTES 7027264
#define COUNTS_OFF  C1_OFF
#define OFFSETS_OFF (C1_OFF + 4096)
#define CURSOR_OFF  (C1_OFF + 8192)
#define SORTED_OFF  C2_OFF

__device__ inline void inv3(const float* b, float* ib) {
    float a00=b[0],a01=b[1],a02=b[2],a10=b[3],a11=b[4],a12=b[5],a20=b[6],a21=b[7],a22=b[8];
    float c00 =  a11*a22 - a12*a21;
    float c01 = -(a10*a22 - a12*a20);
    float c02 =  a10*a21 - a11*a20;
    float c10 = -(a01*a22 - a02*a21);
    float c11 =  a00*a22 - a02*a20;
    float c12 = -(a00*a21 - a01*a20);
    float c20 =  a01*a12 - a02*a11;
    float c21 = -(a00*a12 - a02*a10);
    float c22 =  a00*a11 - a01*a10;
    float det = a00*c00 + a01*c01 + a02*c02;
    float inv = 1.0f/det;
    ib[0]=c00*inv; ib[1]=c10*inv; ib[2]=c20*inv;
    ib[3]=c01*inv; ib[4]=c11*inv; ib[5]=c21*inv;
    ib[6]=c02*inv; ib[7]=c12*inv; ib[8]=c22*inv;
}

// scaled position per dim from coords
__device__ inline void atom_pos(const float* __restrict__ box, float c0, float c1, float c2,
                                float* p) {
    float ib[9]; inv3(box, ib);
    #pragma unroll
    for (int d=0; d<3; ++d)
        p[d] = (c0*ib[0+d] + c1*ib[3+d] + c2*ib[6+d]) * 120.0f;
}

__device__ inline int wrap120(int i) { return ((i % 120) + 120) % 120; }

__global__ void table_kernel(float2* __restrict__ T) {
    int idx = blockIdx.x*blockDim.x + threadIdx.x;
    if (idx >= 120*120) return;
    int z = idx/120, k = idx - z*120;
    int m = (z*k) % 120;
    double ang = (2.0*M_PI/120.0) * (double)m;
    T[idx] = make_float2((float)cos(ang), (float)(-sin(ang)));
}

__global__ void reduce_q_kernel(const float* __restrict__ q, double* __restrict__ acc, int n) {
    int i = blockIdx.x*blockDim.x + threadIdx.x;
    float v = 0.f, v2 = 0.f;
    if (i < n) { v = q[i]; v2 = v*v; }
    #pragma unroll
    for (int o=32;o>0;o>>=1) { v += __shfl_down(v,o,64); v2 += __shfl_down(v2,o,64); }
    __shared__ float s1[4], s2[4];
    int lane = threadIdx.x & 63, w = threadIdx.x >> 6;
    if (lane==0) { s1[w]=v; s2[w]=v2; }
    __syncthreads();
    if (threadIdx.x==0) {
        for (int j=1;j<4;j++) { v += s1[j]; v2 += s2[j]; }
        atomicAdd(&acc[1], (double)v);
        atomicAdd(&acc[2], (double)v2);
    }
}

__global__ void bin_count_kernel(const float* __restrict__ coords,
                                 const float* __restrict__ box,
                                 int* __restrict__ counts, int n) {
    int i = blockIdx.x*blockDim.x + threadIdx.x;
    if (i >= n) return;
    float p[3]; atom_pos(box, coords[3*i], coords[3*i+1], coords[3*i+2], p);
    int t[3];
    #pragma unroll
    for (int d=0; d<3; ++d) t[d] = wrap120((int)floorf(p[d])) / TILE;
    atomicAdd(&counts[(t[0]*NTPD + t[1])*NTPD + t[2]], 1);
}

__global__ void scan_kernel(const int* __restrict__ counts,
                            int* __restrict__ offsets, int* __restrict__ cursor) {
    __shared__ int s[1024];
    int t = threadIdx.x;
    s[t] = (t < NTILE) ? counts[t] : 0;
    __syncthreads();
    for (int d=1; d<1024; d<<=1) {
        int v = (t >= d) ? s[t-d] : 0;
        __syncthreads();
        s[t] += v;
        __syncthreads();
    }
    int excl = (t==0) ? 0 : s[t-1];
    if (t < NTILE) { offsets[t] = excl; cursor[t] = excl; }
    if (t == NTILE-1) offsets[NTILE] = s[t];
}

__global__ void scatter_kernel(const float* __restrict__ coords,
                               const float* __restrict__ box,
                               const float* __restrict__ charges,
                               int* __restrict__ cursor,
                               float4* __restrict__ sorted, int n) {
    int i = blockIdx.x*blockDim.x + threadIdx.x;
    if (i >= n) return;
    float p[3]; atom_pos(box, coords[3*i], coords[3*i+1], coords[3*i+2], p);
    int t[3];
    #pragma unroll
    for (int d=0; d<3; ++d) t[d] = wrap120((int)floorf(p[d])) / TILE;
    int tile = (t[0]*NTPD + t[1])*NTPD + t[2];
    int pdst = atomicAdd(&cursor[tile], 1);
    sorted[pdst] = make_float4(p[0], p[1], p[2], charges[i]);
}

// one block per spatial tile; accumulate footprint in LDS, flush once.
__global__ void __launch_bounds__(256)
spread_tile_kernel(const float4* __restrict__ sorted,
                   const int* __restrict__ offsets,
                   float* __restrict__ mesh) {
    int tile = blockIdx.x;
    int tx = tile / (NTPD*NTPD);
    int rem = tile - tx*NTPD*NTPD;
    int ty = rem / NTPD;
    int tz = rem - ty*NTPD;
    int bx = tx*TILE, by = ty*TILE, bz = tz*TILE;

    __shared__ float accS[FPCELLS];
    __shared__ float wxs[256*6], wys[256*6], wzs[256*6];
    __shared__ int   lcode[256];

    int tid = threadIdx.x;
    for (int i = tid; i < FPCELLS; i += 256) accS[i] = 0.f;

    int beg = offsets[tile], end = offsets[tile+1];
    __syncthreads();

    for (int start = beg; start < end; start += 256) {
        int cnt = min(256, end - start);
        if (tid < cnt) {
            float4 s = sorted[start + tid];
            float p[3] = {s.x, s.y, s.z};
            float q = s.w;
            int li[3];
            #pragma unroll
            for (int d=0; d<3; ++d) {
                float fi0 = floorf(p[d]);
                float x = p[d] - (fi0 + 0.5f);
                float df[6];
                #pragma unroll
                for (int k=0;k<6;++k) df[k] = x - ((float)k - 2.5f);
                float w0 = df[1]*df[2]*df[3]*df[4]*df[5] * (-1.0f/120.0f);
                float w1 = df[0]*df[2]*df[3]*df[4]*df[5] * ( 1.0f/24.0f);
                float w2 = df[0]*df[1]*df[3]*df[4]*df[5] * (-1.0f/12.0f);
                float w3 = df[0]*df[1]*df[2]*df[4]*df[5] * ( 1.0f/12.0f);
                float w4 = df[0]*df[1]*df[2]*df[3]*df[5] * (-1.0f/24.0f);
                float w5 = df[0]*df[1]*df[2]*df[3]*df[4] * ( 1.0f/120.0f);
                float sc = (d==0) ? q : 1.0f;
                float* wdst = (d==0) ? wxs : (d==1) ? wys : wzs;
                wdst[tid*6+0]=w0*sc; wdst[tid*6+1]=w1*sc; wdst[tid*6+2]=w2*sc;
                wdst[tid*6+3]=w3*sc; wdst[tid*6+4]=w4*sc; wdst[tid*6+5]=w5*sc;
                int im = wrap120((int)fi0);
                int base = (d==0)?bx:(d==1)?by:bz;
                li[d] = im - base;            // in [0, TILE)
            }
            lcode[tid] = li[0] | (li[1]<<8) | (li[2]<<16);
        }
        __syncthreads();
        int pairs = cnt * 36;
        for (int p = tid; p < pairs; p += 256) {
            int ai = p / 36;
            int r  = p - ai*36;
            int a  = r / 6;
            int b  = r - a*6;
            int code = lcode[ai];
            int lx = (code & 0xff) + a;
            int ly = ((code >> 8) & 0xff) + b;
            int lz = (code >> 16) & 0xff;
            float wab = wxs[ai*6+a] * wys[ai*6+b];
            int basea = (lx*FP + ly)*FP + lz;
            #pragma unroll
            for (int c=0; c<6; ++c)
                atomicAdd(&accS[basea + c], wab * wzs[ai*6+c]);
        }
        __syncthreads();
    }

    // flush footprint to global mesh
    for (int i = tid; i < FPCELLS; i += 256) {
        float v = accS[i];
        if (v != 0.f) {
            int lx = i / (FP*FP);
            int r  = i - lx*FP*FP;
            int ly = r / FP;
            int lz = r - ly*FP;
            int gx = wrap120(bx - 2 + lx);
            int gy = wrap120(by - 2 + ly);
            int gz = wrap120(bz - 2 + lz);
            atomicAdd(&mesh[(gx*120 + gy)*120 + gz], v);
        }
    }
}

// stage 1: rfft along z. one block per (x,y) line.
__global__ void fft_z_kernel(const float* __restrict__ mesh,
                             const float2* __restrict__ T,
                             float2* __restrict__ C1) {
    int line = blockIdx.x;                 // x*120+y
    __shared__ float lds[120];
    const float* src = mesh + line*120;
    for (int i = threadIdx.x; i < 120; i += 64) lds[i] = src[i];
    __syncthreads();
    int kz = threadIdx.x;
    if (kz < NKZ) {
        float re = 0.f, im = 0.f;
        for (int z=0; z<120; ++z) {
            float v = lds[z];
            float2 t = T[z*120 + kz];
            re = fmaf(v, t.x, re);
            im = fmaf(v, t.y, im);
        }
        C1[line*NKZ + kz] = make_float2(re, im);
    }
}

// stage 2: cfft along y. one block per (x,kz).
__global__ void fft_y_kernel(const float2* __restrict__ C1,
                             const float2* __restrict__ T,
                             float2* __restrict__ C2) {
    int x  = blockIdx.x / NKZ;
    int kz = blockIdx.x - x*NKZ;
    __shared__ float2 lds[120];
    for (int y = threadIdx.x; y < 120; y += 128) lds[y] = C1[(x*120 + y)*NKZ + kz];
    __syncthreads();
    int ky = threadIdx.x;
    if (ky < 120) {
        float re = 0.f, im = 0.f;
        for (int y=0; y<120; ++y) {
            float2 a = lds[y];
            float2 t = T[y*120 + ky];
            re = fmaf(a.x, t.x, fmaf(-a.y, t.y, re));
            im = fmaf(a.x, t.y, fmaf( a.y, t.x, im));
        }
        C2[(x*NKZ + kz)*120 + ky] = make_float2(re, im);
    }
}

// stage 3: cfft along x, fused with energy reduction. one block per (ky,kz).
__global__ void fft_x_energy_kernel(const float2* __restrict__ C2,
                                    const float2* __restrict__ T,
                                    const float* __restrict__ box,
                                    double* __restrict__ acc) {
    int ky = blockIdx.x / NKZ;
    int kz = blockIdx.x - ky*NKZ;
    __shared__ float2 lds[120];
    for (int x = threadIdx.x; x < 120; x += 128) lds[x] = C2[(x*NKZ + kz)*120 + ky];
    __syncthreads();
    float contrib = 0.f;
    int kx = threadIdx.x;
    if (kx < 120) {
        float re = 0.f, im = 0.f;
        for (int x=0; x<120; ++x) {
            float2 a = lds[x];
            float2 t = T[x*120 + kx];
            re = fmaf(a.x, t.x, fmaf(-a.y, t.y, re));
            im = fmaf(a.x, t.y, fmaf( a.y, t.x, im));
        }
        if (!(kx==0 && ky==0 && kz==0)) {
            float mx = (kx < 60) ? (float)kx : (float)(kx - 120);
            float my = (ky < 60) ? (float)ky : (float)(ky - 120);
            float mz = (float)kz;
            float ib[9]; inv3(box, ib);
            const float TWOPI = 6.283185307179586f;
            float k0 = TWOPI*(mx*ib[0] + my*ib[1] + mz*ib[2]);
            float k1 = TWOPI*(mx*ib[3] + my*ib[4] + mz*ib[5]);
            float k2 = TWOPI*(mx*ib[6] + my*ib[7] + mz*ib[8]);
            float ksq = k0*k0 + k1*k1 + k2*k2;
            float G = 12.566370614359172f * __expf(-0.5f*(float)(ALPHA_C*ALPHA_C)*ksq) / ksq;
            float wgt = (kz==0 || kz==60) ? 1.0f : 2.0f;
            contrib = wgt * G * (re*re + im*im);
        }
    }
    float v = contrib;
    #pragma unroll
    for (int o=32;o>0;o>>=1) v += __shfl_down(v,o,64);
    __shared__ float sm[2];
    int lane = threadIdx.x & 63, w = threadIdx.x >> 6;
    if (lane==0) sm[w] = v;
    __syncthreads();
    if (threadIdx.x==0) atomicAdd(&acc[0], (double)(v + sm[1]));
}

__global__ void finalize_kernel(const double* __restrict__ acc,
                                const float* __restrict__ box,
                                float* __restrict__ out) {
    double ek = acc[0], sq = acc[1], sq2 = acc[2];
    double a00=box[0],a01=box[1],a02=box[2],a10=box[3],a11=box[4],a12=box[5],a20=box[6],a21=box[7],a22=box[8];
    double det = a00*(a11*a22-a12*a21) - a01*(a10*a22-a12*a20) + a02*(a10*a21-a11*a20);
    double vol = fabs(det);
    double E = ek/(2.0*vol)
             - 0.5*sqrt(2.0/M_PI)/ALPHA_C * sq2
             - M_PI*ALPHA_C*ALPHA_C * sq*sq / vol;
    out[0] = (float)E;
}

extern "C" void kernel_launch(void* const* d_in, const int* in_sizes, int n_in,
                              void* d_out, int out_size, void* d_ws, size_t ws_size,
                              hipStream_t stream) {
    const float* coords  = (const float*)d_in[0];
    const float* box     = (const float*)d_in[1];
    const float* charges = (const float*)d_in[2];
    int n = in_sizes[0] / 3;

    char* ws = (char*)d_ws;
    double* acc   = (double*)(ws + ACC_OFF);
    float2* T     = (float2*)(ws + TAB_OFF);
    float*  mesh  = (float*) (ws + MESH_OFF);
    float2* C1    = (float2*)(ws + C1_OFF);
    float2* C2    = (float2*)(ws + C2_OFF);
    int* counts   = (int*)(ws + COUNTS_OFF);
    int* offsets  = (int*)(ws + OFFSETS_OFF);
    int* cursor   = (int*)(ws + CURSOR_OFF);
    float4* sorted= (float4*)(ws + SORTED_OFF);

    int gA = (n + 255)/256;
    hipMemsetAsync(d_ws, 0, ZERO_BYTES, stream);          // acc + T + mesh
    hipMemsetAsync(ws + COUNTS_OFF, 0, 4096, stream);     // tile counts
    table_kernel<<<(14400+255)/256, 256, 0, stream>>>(T);
    reduce_q_kernel<<<gA, 256, 0, stream>>>(charges, acc, n);
    bin_count_kernel<<<gA, 256, 0, stream>>>(coords, box, counts, n);
    scan_kernel<<<1, 1024, 0, stream>>>(counts, offsets, cursor);
    scatter_kernel<<<gA, 256, 0, stream>>>(coords, box, charges, cursor, sorted, n);
    spread_tile_kernel<<<NTILE, 256, 0, stream>>>(sorted, offsets, mesh);
    fft_z_kernel<<<120*120, 64, 0, stream>>>(mesh, T, C1);
    fft_y_kernel<<<120*NKZ, 128, 0, stream>>>(C1, T, C2);
    fft_x_energy_kernel<<<120*NKZ, 128, 0, stream>>>(C2, T, box, acc);
    finalize_kernel<<<1, 1, 0, stream>>>(acc, box, (float*)d_out);
}

// Round 3
// 458.954 us; speedup vs baseline: 3.5287x; 1.5805x over previous
//
#include <hip/hip_runtime.h>
#include <math.h>

#define NMESH 120
#define NKZ 61            // rfft half-spectrum along z
#define NTOT (120*120*120)
#define ALPHA_C 1.0

#define TILE 12           // mesh cells per tile per dim
#define NTPD 10           // tiles per dim
#define NTILE 1000
#define FP 17             // footprint per dim: TILE + 5
#define FPCELLS (FP*FP*FP)   // 4913

#define YCH 30            // y-lines per fft_z block

// ---- workspace layout (bytes) ----
// [0,24)        : 3 doubles: ek_acc, sq_acc, sq2_acc
// [64,115264)   : float2 T[120*120] twiddle table, T[z*120+k] = e^{-2pi i z k/120}
// [115264, +6912000)  : float mesh[120^3]
// [7027264, +7027200) : float2 C1[x][kz][y]  — ALSO (before fft_z) bin ints
// [14054464,+7027200) : float2 C2[kz][ky][x] — ALSO (before fft_y) sorted float4 atoms
#define ACC_OFF   0
#define TAB_OFF   64
#define MESH_OFF  115264
#define C1_OFF    7027264
#define C2_OFF    14054464
#define ZERO_BYTES 7027264
#define COUNTS_OFF  C1_OFF
#define OFFSETS_OFF (C1_OFF + 4096)
#define CURSOR_OFF  (C1_OFF + 8192)
#define SORTED_OFF  C2_OFF

__device__ inline void inv3(const float* b, float* ib) {
    float a00=b[0],a01=b[1],a02=b[2],a10=b[3],a11=b[4],a12=b[5],a20=b[6],a21=b[7],a22=b[8];
    float c00 =  a11*a22 - a12*a21;
    float c01 = -(a10*a22 - a12*a20);
    float c02 =  a10*a21 - a11*a20;
    float c10 = -(a01*a22 - a02*a21);
    float c11 =  a00*a22 - a02*a20;
    float c12 = -(a00*a21 - a01*a20);
    float c20 =  a01*a12 - a02*a11;
    float c21 = -(a00*a12 - a02*a10);
    float c22 =  a00*a11 - a01*a10;
    float det = a00*c00 + a01*c01 + a02*c02;
    float inv = 1.0f/det;
    ib[0]=c00*inv; ib[1]=c10*inv; ib[2]=c20*inv;
    ib[3]=c01*inv; ib[4]=c11*inv; ib[5]=c21*inv;
    ib[6]=c02*inv; ib[7]=c12*inv; ib[8]=c22*inv;
}

__device__ inline void atom_pos(const float* __restrict__ box, float c0, float c1, float c2,
                                float* p) {
    float ib[9]; inv3(box, ib);
    #pragma unroll
    for (int d=0; d<3; ++d)
        p[d] = (c0*ib[0+d] + c1*ib[3+d] + c2*ib[6+d]) * 120.0f;
}

__device__ inline int wrap120(int i) { return ((i % 120) + 120) % 120; }

__global__ void table_kernel(float2* __restrict__ T) {
    int idx = blockIdx.x*blockDim.x + threadIdx.x;
    if (idx >= 120*120) return;
    int z = idx/120, k = idx - z*120;
    int m = (z*k) % 120;
    double ang = (2.0*M_PI/120.0) * (double)m;
    T[idx] = make_float2((float)cos(ang), (float)(-sin(ang)));
}

__global__ void reduce_q_kernel(const float* __restrict__ q, double* __restrict__ acc, int n) {
    int i = blockIdx.x*blockDim.x + threadIdx.x;
    float v = 0.f, v2 = 0.f;
    if (i < n) { v = q[i]; v2 = v*v; }
    #pragma unroll
    for (int o=32;o>0;o>>=1) { v += __shfl_down(v,o,64); v2 += __shfl_down(v2,o,64); }
    __shared__ float s1[4], s2[4];
    int lane = threadIdx.x & 63, w = threadIdx.x >> 6;
    if (lane==0) { s1[w]=v; s2[w]=v2; }
    __syncthreads();
    if (threadIdx.x==0) {
        for (int j=1;j<4;j++) { v += s1[j]; v2 += s2[j]; }
        atomicAdd(&acc[1], (double)v);
        atomicAdd(&acc[2], (double)v2);
    }
}

__global__ void bin_count_kernel(const float* __restrict__ coords,
                                 const float* __restrict__ box,
                                 int* __restrict__ counts, int n) {
    int i = blockIdx.x*blockDim.x + threadIdx.x;
    if (i >= n) return;
    float p[3]; atom_pos(box, coords[3*i], coords[3*i+1], coords[3*i+2], p);
    int t[3];
    #pragma unroll
    for (int d=0; d<3; ++d) t[d] = wrap120((int)floorf(p[d])) / TILE;
    atomicAdd(&counts[(t[0]*NTPD + t[1])*NTPD + t[2]], 1);
}

__global__ void scan_kernel(const int* __restrict__ counts,
                            int* __restrict__ offsets, int* __restrict__ cursor) {
    __shared__ int s[1024];
    int t = threadIdx.x;
    s[t] = (t < NTILE) ? counts[t] : 0;
    __syncthreads();
    for (int d=1; d<1024; d<<=1) {
        int v = (t >= d) ? s[t-d] : 0;
        __syncthreads();
        s[t] += v;
        __syncthreads();
    }
    int excl = (t==0) ? 0 : s[t-1];
    if (t < NTILE) { offsets[t] = excl; cursor[t] = excl; }
    if (t == NTILE-1) offsets[NTILE] = s[t];
}

__global__ void scatter_kernel(const float* __restrict__ coords,
                               const float* __restrict__ box,
                               const float* __restrict__ charges,
                               int* __restrict__ cursor,
                               float4* __restrict__ sorted, int n) {
    int i = blockIdx.x*blockDim.x + threadIdx.x;
    if (i >= n) return;
    float p[3]; atom_pos(box, coords[3*i], coords[3*i+1], coords[3*i+2], p);
    int t[3];
    #pragma unroll
    for (int d=0; d<3; ++d) t[d] = wrap120((int)floorf(p[d])) / TILE;
    int tile = (t[0]*NTPD + t[1])*NTPD + t[2];
    int pdst = atomicAdd(&cursor[tile], 1);
    sorted[pdst] = make_float4(p[0], p[1], p[2], charges[i]);
}

// one block per spatial tile; accumulate footprint in LDS, flush once.
__global__ void __launch_bounds__(256)
spread_tile_kernel(const float4* __restrict__ sorted,
                   const int* __restrict__ offsets,
                   float* __restrict__ mesh) {
    int tile = blockIdx.x;
    int tx = tile / (NTPD*NTPD);
    int rem = tile - tx*NTPD*NTPD;
    int ty = rem / NTPD;
    int tz = rem - ty*NTPD;
    int bx = tx*TILE, by = ty*TILE, bz = tz*TILE;

    __shared__ float accS[FPCELLS];
    __shared__ float wxs[256*6], wys[256*6], wzs[256*6];
    __shared__ int   lcode[256];

    int tid = threadIdx.x;
    for (int i = tid; i < FPCELLS; i += 256) accS[i] = 0.f;

    int beg = offsets[tile], end = offsets[tile+1];
    __syncthreads();

    for (int start = beg; start < end; start += 256) {
        int cnt = min(256, end - start);
        if (tid < cnt) {
            float4 s = sorted[start + tid];
            float p[3] = {s.x, s.y, s.z};
            float q = s.w;
            int li[3];
            #pragma unroll
            for (int d=0; d<3; ++d) {
                float fi0 = floorf(p[d]);
                float x = p[d] - (fi0 + 0.5f);
                float df[6];
                #pragma unroll
                for (int k=0;k<6;++k) df[k] = x - ((float)k - 2.5f);
                float w0 = df[1]*df[2]*df[3]*df[4]*df[5] * (-1.0f/120.0f);
                float w1 = df[0]*df[2]*df[3]*df[4]*df[5] * ( 1.0f/24.0f);
                float w2 = df[0]*df[1]*df[3]*df[4]*df[5] * (-1.0f/12.0f);
                float w3 = df[0]*df[1]*df[2]*df[4]*df[5] * ( 1.0f/12.0f);
                float w4 = df[0]*df[1]*df[2]*df[3]*df[5] * (-1.0f/24.0f);
                float w5 = df[0]*df[1]*df[2]*df[3]*df[4] * ( 1.0f/120.0f);
                float sc = (d==0) ? q : 1.0f;
                float* wdst = (d==0) ? wxs : (d==1) ? wys : wzs;
                wdst[tid*6+0]=w0*sc; wdst[tid*6+1]=w1*sc; wdst[tid*6+2]=w2*sc;
                wdst[tid*6+3]=w3*sc; wdst[tid*6+4]=w4*sc; wdst[tid*6+5]=w5*sc;
                int im = wrap120((int)fi0);
                int base = (d==0)?bx:(d==1)?by:bz;
                li[d] = im - base;            // in [0, TILE)
            }
            lcode[tid] = li[0] | (li[1]<<8) | (li[2]<<16);
        }
        __syncthreads();
        int pairs = cnt * 36;
        for (int p = tid; p < pairs; p += 256) {
            int ai = p / 36;
            int r  = p - ai*36;
            int a  = r / 6;
            int b  = r - a*6;
            int code = lcode[ai];
            int lx = (code & 0xff) + a;
            int ly = ((code >> 8) & 0xff) + b;
            int lz = (code >> 16) & 0xff;
            float wab = wxs[ai*6+a] * wys[ai*6+b];
            int basea = (lx*FP + ly)*FP + lz;
            #pragma unroll
            for (int c=0; c<6; ++c)
                atomicAdd(&accS[basea + c], wab * wzs[ai*6+c]);
        }
        __syncthreads();
    }

    for (int i = tid; i < FPCELLS; i += 256) {
        float v = accS[i];
        if (v != 0.f) {
            int lx = i / (FP*FP);
            int r  = i - lx*FP*FP;
            int ly = r / FP;
            int lz = r - ly*FP;
            int gx = wrap120(bx - 2 + lx);
            int gy = wrap120(by - 2 + ly);
            int gz = wrap120(bz - 2 + lz);
            atomicAdd(&mesh[(gx*120 + gy)*120 + gz], v);
        }
    }
}

// stage 1: rfft along z. block = (x, 30-line y-chunk). out C1[x][kz][y].
__global__ void __launch_bounds__(256)
fft_z_kernel(const float* __restrict__ mesh,
             const float2* __restrict__ T,
             float2* __restrict__ C1) {
    int x  = blockIdx.x >> 2;
    int y0 = (blockIdx.x & 3) * YCH;
    __shared__ float lds[YCH][121];
    const float* src = mesh + (x*120 + y0)*120;    // contiguous 30*120 floats
    for (int i = threadIdx.x; i < YCH*120; i += 256) {
        int yl = i / 120, z = i - yl*120;
        lds[yl][z] = src[i];
    }
    __syncthreads();
    for (int o = threadIdx.x; o < YCH*NKZ; o += 256) {
        int kz = o / YCH, yl = o - kz*YCH;         // y fastest -> coalesced write
        float re = 0.f, im = 0.f;
        for (int z=0; z<120; ++z) {
            float v = lds[yl][z];
            float2 t = T[z*120 + kz];
            re = fmaf(v, t.x, re);
            im = fmaf(v, t.y, im);
        }
        C1[(x*NKZ + kz)*120 + y0 + yl] = make_float2(re, im);
    }
}

// stage 2: cfft along y. block = (8 consecutive x, kz). out C2[kz][ky][x].
__global__ void __launch_bounds__(256)
fft_y_kernel(const float2* __restrict__ C1,
             const float2* __restrict__ T,
             float2* __restrict__ C2) {
    int xc = blockIdx.x / NKZ;
    int kz = blockIdx.x - xc*NKZ;
    int x0 = xc * 8;
    __shared__ float2 lds[8][121];
    for (int i = threadIdx.x; i < 8*120; i += 256) {
        int xo = i / 120, y = i - xo*120;
        lds[xo][y] = C1[((x0+xo)*NKZ + kz)*120 + y];   // 960B coalesced runs
    }
    __syncthreads();
    for (int o = threadIdx.x; o < 960; o += 256) {
        int ky = o >> 3, xo = o & 7;                   // x fastest -> coalesced write
        float re = 0.f, im = 0.f;
        for (int y=0; y<120; ++y) {
            float2 a = lds[xo][y];
            float2 t = T[y*120 + ky];
            re = fmaf(a.x, t.x, fmaf(-a.y, t.y, re));
            im = fmaf(a.x, t.y, fmaf( a.y, t.x, im));
        }
        C2[(kz*120 + ky)*120 + x0 + xo] = make_float2(re, im);
    }
}

// stage 3: cfft along x + G-weighted energy reduction. block = (kz, 8-ky chunk).
__global__ void __launch_bounds__(256)
fft_x_energy_kernel(const float2* __restrict__ C2,
                    const float2* __restrict__ T,
                    const float* __restrict__ box,
                    double* __restrict__ acc) {
    int kz  = blockIdx.x / 15;
    int ky0 = (blockIdx.x - kz*15) * 8;
    __shared__ float2 lds[8][121];
    const float2* src = C2 + (kz*120 + ky0)*120;       // contiguous 7680B slab
    for (int i = threadIdx.x; i < 960; i += 256) {
        int kyo = i / 120, x = i - kyo*120;
        lds[kyo][x] = src[i];
    }
    __syncthreads();
    float ib[9]; inv3(box, ib);
    const float TWOPI = 6.283185307179586f;
    float wz = (kz==0 || kz==60) ? 1.0f : 2.0f;
    float contrib = 0.f;
    for (int o = threadIdx.x; o < 960; o += 256) {
        int kyo = o / 120, kx = o - kyo*120;           // kx fastest: T coalesced, LDS broadcast
        int ky = ky0 + kyo;
        float re = 0.f, im = 0.f;
        for (int x=0; x<120; ++x) {
            float2 a = lds[kyo][x];
            float2 t = T[x*120 + kx];
            re = fmaf(a.x, t.x, fmaf(-a.y, t.y, re));
            im = fmaf(a.x, t.y, fmaf( a.y, t.x, im));
        }
        if (!(kx==0 && ky==0 && kz==0)) {
            float mx = (kx < 60) ? (float)kx : (float)(kx - 120);
            float my = (ky < 60) ? (float)ky : (float)(ky - 120);
            float mz = (float)kz;
            float k0 = TWOPI*(mx*ib[0] + my*ib[1] + mz*ib[2]);
            float k1 = TWOPI*(mx*ib[3] + my*ib[4] + mz*ib[5]);
            float k2 = TWOPI*(mx*ib[6] + my*ib[7] + mz*ib[8]);
            float ksq = k0*k0 + k1*k1 + k2*k2;
            float G = 12.566370614359172f * __expf(-0.5f*(float)(ALPHA_C*ALPHA_C)*ksq) / ksq;
            contrib += wz * G * (re*re + im*im);
        }
    }
    #pragma unroll
    for (int o=32;o>0;o>>=1) contrib += __shfl_down(contrib,o,64);
    __shared__ float sm[4];
    int lane = threadIdx.x & 63, w = threadIdx.x >> 6;
    if (lane==0) sm[w] = contrib;
    __syncthreads();
    if (threadIdx.x==0)
        atomicAdd(&acc[0], (double)(sm[0]+sm[1]+sm[2]+sm[3]));
}

__global__ void finalize_kernel(const double* __restrict__ acc,
                                const float* __restrict__ box,
                                float* __restrict__ out) {
    double ek = acc[0], sq = acc[1], sq2 = acc[2];
    double a00=box[0],a01=box[1],a02=box[2],a10=box[3],a11=box[4],a12=box[5],a20=box[6],a21=box[7],a22=box[8];
    double det = a00*(a11*a22-a12*a21) - a01*(a10*a22-a12*a20) + a02*(a10*a21-a11*a20);
    double vol = fabs(det);
    double E = ek/(2.0*vol)
             - 0.5*sqrt(2.0/M_PI)/ALPHA_C * sq2
             - M_PI*ALPHA_C*ALPHA_C * sq*sq / vol;
    out[0] = (float)E;
}

extern "C" void kernel_launch(void* const* d_in, const int* in_sizes, int n_in,
                              void* d_out, int out_size, void* d_ws, size_t ws_size,
                              hipStream_t stream) {
    const float* coords  = (const float*)d_in[0];
    const float* box     = (const float*)d_in[1];
    const float* charges = (const float*)d_in[2];
    int n = in_sizes[0] / 3;

    char* ws = (char*)d_ws;
    double* acc   = (double*)(ws + ACC_OFF);
    float2* T     = (float2*)(ws + TAB_OFF);
    float*  mesh  = (float*) (ws + MESH_OFF);
    float2* C1    = (float2*)(ws + C1_OFF);
    float2* C2    = (float2*)(ws + C2_OFF);
    int* counts   = (int*)(ws + COUNTS_OFF);
    int* offsets  = (int*)(ws + OFFSETS_OFF);
    int* cursor   = (int*)(ws + CURSOR_OFF);
    float4* sorted= (float4*)(ws + SORTED_OFF);

    int gA = (n + 255)/256;
    hipMemsetAsync(d_ws, 0, ZERO_BYTES, stream);          // acc + T + mesh
    hipMemsetAsync(ws + COUNTS_OFF, 0, 4096, stream);     // tile counts
    table_kernel<<<(14400+255)/256, 256, 0, stream>>>(T);
    reduce_q_kernel<<<gA, 256, 0, stream>>>(charges, acc, n);
    bin_count_kernel<<<gA, 256, 0, stream>>>(coords, box, counts, n);
    scan_kernel<<<1, 1024, 0, stream>>>(counts, offsets, cursor);
    scatter_kernel<<<gA, 256, 0, stream>>>(coords, box, charges, cursor, sorted, n);
    spread_tile_kernel<<<NTILE, 256, 0, stream>>>(sorted, offsets, mesh);
    fft_z_kernel<<<120*4, 256, 0, stream>>>(mesh, T, C1);
    fft_y_kernel<<<15*NKZ, 256, 0, stream>>>(C1, T, C2);
    fft_x_energy_kernel<<<NKZ*15, 256, 0, stream>>>(C2, T, box, acc);
    finalize_kernel<<<1, 1, 0, stream>>>(acc, box, (float*)d_out);
}

// Round 4
// 451.194 us; speedup vs baseline: 3.5894x; 1.0172x over previous
//
#include <hip/hip_runtime.h>
#include <math.h>

#define NMESH 120
#define NKZ 61            // rfft half-spectrum along z
#define NTOT (120*120*120)
#define ALPHA_C 1.0

#define TILE 12           // mesh cells per tile per dim
#define NTPD 10           // tiles per dim
#define NTILE 1000
#define FP 17             // footprint per dim: TILE + 5
#define FPCELLS (FP*FP*FP)   // 4913

#define YCH 30            // y-lines per fft_z block

// ---- workspace layout (bytes) ----
// [0,24)        : 3 doubles: ek_acc, sq_acc, sq2_acc
// [64,115264)   : float2 T[120*120] twiddle table
// [115264, +6912000)  : float mesh[120^3]
// [7027264, +7027200) : float2 C1[x][kz][y]  — ALSO (before fft_z) bin ints
// [14054464,+7027200) : float2 C2[kz][ky][x] — ALSO (before fft_y) sorted float4 atoms
#define ACC_OFF   0
#define TAB_OFF   64
#define MESH_OFF  115264
#define C1_OFF    7027264
#define C2_OFF    14054464
#define ZERO_BYTES 7027264
#define COUNTS_OFF  C1_OFF
#define OFFSETS_OFF (C1_OFF + 4096)
#define CURSOR_OFF  (C1_OFF + 8192)
#define SORTED_OFF  C2_OFF

__device__ inline void inv3(const float* b, float* ib) {
    float a00=b[0],a01=b[1],a02=b[2],a10=b[3],a11=b[4],a12=b[5],a20=b[6],a21=b[7],a22=b[8];
    float c00 =  a11*a22 - a12*a21;
    float c01 = -(a10*a22 - a12*a20);
    float c02 =  a10*a21 - a11*a20;
    float c10 = -(a01*a22 - a02*a21);
    float c11 =  a00*a22 - a02*a20;
    float c12 = -(a00*a21 - a01*a20);
    float c20 =  a01*a12 - a02*a11;
    float c21 = -(a00*a12 - a02*a10);
    float c22 =  a00*a11 - a01*a10;
    float det = a00*c00 + a01*c01 + a02*c02;
    float inv = 1.0f/det;
    ib[0]=c00*inv; ib[1]=c10*inv; ib[2]=c20*inv;
    ib[3]=c01*inv; ib[4]=c11*inv; ib[5]=c21*inv;
    ib[6]=c02*inv; ib[7]=c12*inv; ib[8]=c22*inv;
}

__device__ inline void atom_pos(const float* __restrict__ box, float c0, float c1, float c2,
                                float* p) {
    float ib[9]; inv3(box, ib);
    #pragma unroll
    for (int d=0; d<3; ++d)
        p[d] = (c0*ib[0+d] + c1*ib[3+d] + c2*ib[6+d]) * 120.0f;
}

__device__ inline int wrap120(int i) { return ((i % 120) + 120) % 120; }

// order-6 Lagrange weights for one dim; x = pos - (floor(pos)+0.5)
__device__ inline void lag6(float x, float* w) {
    float df[6];
    #pragma unroll
    for (int k=0;k<6;++k) df[k] = x - ((float)k - 2.5f);
    w[0] = df[1]*df[2]*df[3]*df[4]*df[5] * (-1.0f/120.0f);
    w[1] = df[0]*df[2]*df[3]*df[4]*df[5] * ( 1.0f/24.0f);
    w[2] = df[0]*df[1]*df[3]*df[4]*df[5] * (-1.0f/12.0f);
    w[3] = df[0]*df[1]*df[2]*df[4]*df[5] * ( 1.0f/12.0f);
    w[4] = df[0]*df[1]*df[2]*df[3]*df[5] * (-1.0f/24.0f);
    w[5] = df[0]*df[1]*df[2]*df[3]*df[4] * ( 1.0f/120.0f);
}

__global__ void table_kernel(float2* __restrict__ T) {
    int idx = blockIdx.x*blockDim.x + threadIdx.x;
    if (idx >= 120*120) return;
    int z = idx/120, k = idx - z*120;
    int m = (z*k) % 120;
    double ang = (2.0*M_PI/120.0) * (double)m;
    T[idx] = make_float2((float)cos(ang), (float)(-sin(ang)));
}

// fused: tile histogram + sum(q) + sum(q^2)
__global__ void bin_count_q_kernel(const float* __restrict__ coords,
                                   const float* __restrict__ box,
                                   const float* __restrict__ charges,
                                   int* __restrict__ counts,
                                   double* __restrict__ acc, int n) {
    int i = blockIdx.x*blockDim.x + threadIdx.x;
    float v = 0.f, v2 = 0.f;
    if (i < n) {
        float p[3]; atom_pos(box, coords[3*i], coords[3*i+1], coords[3*i+2], p);
        int t[3];
        #pragma unroll
        for (int d=0; d<3; ++d) t[d] = wrap120((int)floorf(p[d])) / TILE;
        atomicAdd(&counts[(t[0]*NTPD + t[1])*NTPD + t[2]], 1);
        v = charges[i]; v2 = v*v;
    }
    #pragma unroll
    for (int o=32;o>0;o>>=1) { v += __shfl_down(v,o,64); v2 += __shfl_down(v2,o,64); }
    __shared__ float s1[4], s2[4];
    int lane = threadIdx.x & 63, w = threadIdx.x >> 6;
    if (lane==0) { s1[w]=v; s2[w]=v2; }
    __syncthreads();
    if (threadIdx.x==0) {
        for (int j=1;j<4;j++) { v += s1[j]; v2 += s2[j]; }
        atomicAdd(&acc[1], (double)v);
        atomicAdd(&acc[2], (double)v2);
    }
}

__global__ void scan_kernel(const int* __restrict__ counts,
                            int* __restrict__ offsets, int* __restrict__ cursor) {
    __shared__ int s[1024];
    int t = threadIdx.x;
    s[t] = (t < NTILE) ? counts[t] : 0;
    __syncthreads();
    for (int d=1; d<1024; d<<=1) {
        int v = (t >= d) ? s[t-d] : 0;
        __syncthreads();
        s[t] += v;
        __syncthreads();
    }
    int excl = (t==0) ? 0 : s[t-1];
    if (t < NTILE) { offsets[t] = excl; cursor[t] = excl; }
    if (t == NTILE-1) offsets[NTILE] = s[t];
}

__global__ void scatter_kernel(const float* __restrict__ coords,
                               const float* __restrict__ box,
                               const float* __restrict__ charges,
                               int* __restrict__ cursor,
                               float4* __restrict__ sorted, int n) {
    int i = blockIdx.x*blockDim.x + threadIdx.x;
    if (i >= n) return;
    float p[3]; atom_pos(box, coords[3*i], coords[3*i+1], coords[3*i+2], p);
    int t[3];
    #pragma unroll
    for (int d=0; d<3; ++d) t[d] = wrap120((int)floorf(p[d])) / TILE;
    int tile = (t[0]*NTPD + t[1])*NTPD + t[2];
    int pdst = atomicAdd(&cursor[tile], 1);
    sorted[pdst] = make_float4(p[0], p[1], p[2], charges[i]);
}

// one block per spatial tile. thread = (atom, x-slice) pair; weights in
// registers; 36 back-to-back LDS atomics per thread; flush once.
__global__ void __launch_bounds__(512, 8)
spread_tile_kernel(const float4* __restrict__ sorted,
                   const int* __restrict__ offsets,
                   float* __restrict__ mesh) {
    int tile = blockIdx.x;
    int tx = tile / (NTPD*NTPD);
    int rem = tile - tx*NTPD*NTPD;
    int ty = rem / NTPD;
    int tz = rem - ty*NTPD;
    int bx = tx*TILE, by = ty*TILE, bz = tz*TILE;

    __shared__ float  accS[FPCELLS];
    __shared__ float4 atomS[256];

    int tid = threadIdx.x;
    for (int i = tid; i < FPCELLS; i += 512) accS[i] = 0.f;

    int beg = offsets[tile], end = offsets[tile+1];

    for (int start = beg; start < end; start += 256) {
        int cnt = min(256, end - start);
        if (tid < cnt) atomS[tid] = sorted[start + tid];
        __syncthreads();                       // atomS ready; accS init/prev-round done
        int pairs = cnt * 6;
        for (int p = tid; p < pairs; p += 512) {
            int ai = p / 6;
            int a  = p - ai*6;
            float4 s = atomS[ai];
            // x dim: need only weight a and the slice index
            float fx = floorf(s.x);
            float wx[6]; lag6(s.x - (fx + 0.5f), wx);
            float wxa = ((a==0)?wx[0]:(a==1)?wx[1]:(a==2)?wx[2]:(a==3)?wx[3]:(a==4)?wx[4]:wx[5]) * s.w;
            int lx = wrap120((int)fx) - bx + a;          // [0,17)
            float fy = floorf(s.y);
            float wy[6]; lag6(s.y - (fy + 0.5f), wy);
            int ly = wrap120((int)fy) - by;              // [0,12)
            float fz = floorf(s.z);
            float wz[6]; lag6(s.z - (fz + 0.5f), wz);
            int lz = wrap120((int)fz) - bz;              // [0,12)
            int baseXY = (lx*FP + ly)*FP + lz;
            #pragma unroll
            for (int b=0;b<6;++b) {
                float wab = wxa * wy[b];
                int base = baseXY + b*FP;
                #pragma unroll
                for (int c=0;c<6;++c)
                    atomicAdd(&accS[base + c], wab * wz[c]);
            }
        }
        __syncthreads();                       // before atomS overwrite / flush
    }
    __syncthreads();

    for (int i = tid; i < FPCELLS; i += 512) {
        float v = accS[i];
        if (v != 0.f) {
            int lx = i / (FP*FP);
            int r  = i - lx*FP*FP;
            int ly = r / FP;
            int lz = r - ly*FP;
            int gx = wrap120(bx - 2 + lx);
            int gy = wrap120(by - 2 + ly);
            int gz = wrap120(bz - 2 + lz);
            atomicAdd(&mesh[(gx*120 + gy)*120 + gz], v);
        }
    }
}

// stage 1: rfft along z. block = (x, 30-line y-chunk). out C1[x][kz][y].
__global__ void __launch_bounds__(256)
fft_z_kernel(const float* __restrict__ mesh,
             const float2* __restrict__ T,
             float2* __restrict__ C1) {
    int x  = blockIdx.x >> 2;
    int y0 = (blockIdx.x & 3) * YCH;
    __shared__ float lds[YCH][121];
    const float* src = mesh + (x*120 + y0)*120;
    for (int i = threadIdx.x; i < YCH*120; i += 256) {
        int yl = i / 120, z = i - yl*120;
        lds[yl][z] = src[i];
    }
    __syncthreads();
    for (int o = threadIdx.x; o < YCH*NKZ; o += 256) {
        int kz = o / YCH, yl = o - kz*YCH;
        float re = 0.f, im = 0.f;
        for (int z=0; z<120; ++z) {
            float v = lds[yl][z];
            float2 t = T[z*120 + kz];
            re = fmaf(v, t.x, re);
            im = fmaf(v, t.y, im);
        }
        C1[(x*NKZ + kz)*120 + y0 + yl] = make_float2(re, im);
    }
}

// stage 2: cfft along y. block = (8 consecutive x, kz). out C2[kz][ky][x].
__global__ void __launch_bounds__(256)
fft_y_kernel(const float2* __restrict__ C1,
             const float2* __restrict__ T,
             float2* __restrict__ C2) {
    int xc = blockIdx.x / NKZ;
    int kz = blockIdx.x - xc*NKZ;
    int x0 = xc * 8;
    __shared__ float2 lds[8][121];
    for (int i = threadIdx.x; i < 8*120; i += 256) {
        int xo = i / 120, y = i - xo*120;
        lds[xo][y] = C1[((x0+xo)*NKZ + kz)*120 + y];
    }
    __syncthreads();
    for (int o = threadIdx.x; o < 960; o += 256) {
        int ky = o >> 3, xo = o & 7;
        float re = 0.f, im = 0.f;
        for (int y=0; y<120; ++y) {
            float2 a = lds[xo][y];
            float2 t = T[y*120 + ky];
            re = fmaf(a.x, t.x, fmaf(-a.y, t.y, re));
            im = fmaf(a.x, t.y, fmaf( a.y, t.x, im));
        }
        C2[(kz*120 + ky)*120 + x0 + xo] = make_float2(re, im);
    }
}

// stage 3: cfft along x + G-weighted energy reduction. block = (kz, 8-ky chunk).
__global__ void __launch_bounds__(256)
fft_x_energy_kernel(const float2* __restrict__ C2,
                    const float2* __restrict__ T,
                    const float* __restrict__ box,
                    double* __restrict__ acc) {
    int kz  = blockIdx.x / 15;
    int ky0 = (blockIdx.x - kz*15) * 8;
    __shared__ float2 lds[8][121];
    const float2* src = C2 + (kz*120 + ky0)*120;
    for (int i = threadIdx.x; i < 960; i += 256) {
        int kyo = i / 120, x = i - kyo*120;
        lds[kyo][x] = src[i];
    }
    __syncthreads();
    float ib[9]; inv3(box, ib);
    const float TWOPI = 6.283185307179586f;
    float wzf = (kz==0 || kz==60) ? 1.0f : 2.0f;
    float contrib = 0.f;
    for (int o = threadIdx.x; o < 960; o += 256) {
        int kyo = o / 120, kx = o - kyo*120;
        int ky = ky0 + kyo;
        float re = 0.f, im = 0.f;
        for (int x=0; x<120; ++x) {
            float2 a = lds[kyo][x];
            float2 t = T[x*120 + kx];
            re = fmaf(a.x, t.x, fmaf(-a.y, t.y, re));
            im = fmaf(a.x, t.y, fmaf( a.y, t.x, im));
        }
        if (!(kx==0 && ky==0 && kz==0)) {
            float mx = (kx < 60) ? (float)kx : (float)(kx - 120);
            float my = (ky < 60) ? (float)ky : (float)(ky - 120);
            float mz = (float)kz;
            float k0 = TWOPI*(mx*ib[0] + my*ib[1] + mz*ib[2]);
            float k1 = TWOPI*(mx*ib[3] + my*ib[4] + mz*ib[5]);
            float k2 = TWOPI*(mx*ib[6] + my*ib[7] + mz*ib[8]);
            float ksq = k0*k0 + k1*k1 + k2*k2;
            float G = 12.566370614359172f * __expf(-0.5f*(float)(ALPHA_C*ALPHA_C)*ksq) / ksq;
            contrib += wzf * G * (re*re + im*im);
        }
    }
    #pragma unroll
    for (int o=32;o>0;o>>=1) contrib += __shfl_down(contrib,o,64);
    __shared__ float sm[4];
    int lane = threadIdx.x & 63, w = threadIdx.x >> 6;
    if (lane==0) sm[w] = contrib;
    __syncthreads();
    if (threadIdx.x==0)
        atomicAdd(&acc[0], (double)(sm[0]+sm[1]+sm[2]+sm[3]));
}

__global__ void finalize_kernel(const double* __restrict__ acc,
                                const float* __restrict__ box,
                                float* __restrict__ out) {
    double ek = acc[0], sq = acc[1], sq2 = acc[2];
    double a00=box[0],a01=box[1],a02=box[2],a10=box[3],a11=box[4],a12=box[5],a20=box[6],a21=box[7],a22=box[8];
    double det = a00*(a11*a22-a12*a21) - a01*(a10*a22-a12*a20) + a02*(a10*a21-a11*a20);
    double vol = fabs(det);
    double E = ek/(2.0*vol)
             - 0.5*sqrt(2.0/M_PI)/ALPHA_C * sq2
             - M_PI*ALPHA_C*ALPHA_C * sq*sq / vol;
    out[0] = (float)E;
}

extern "C" void kernel_launch(void* const* d_in, const int* in_sizes, int n_in,
                              void* d_out, int out_size, void* d_ws, size_t ws_size,
                              hipStream_t stream) {
    const float* coords  = (const float*)d_in[0];
    const float* box     = (const float*)d_in[1];
    const float* charges = (const float*)d_in[2];
    int n = in_sizes[0] / 3;

    char* ws = (char*)d_ws;
    double* acc   = (double*)(ws + ACC_OFF);
    float2* T     = (float2*)(ws + TAB_OFF);
    float*  mesh  = (float*) (ws + MESH_OFF);
    float2* C1    = (float2*)(ws + C1_OFF);
    float2* C2    = (float2*)(ws + C2_OFF);
    int* counts   = (int*)(ws + COUNTS_OFF);
    int* offsets  = (int*)(ws + OFFSETS_OFF);
    int* cursor   = (int*)(ws + CURSOR_OFF);
    float4* sorted= (float4*)(ws + SORTED_OFF);

    int gA = (n + 255)/256;
    hipMemsetAsync(d_ws, 0, ZERO_BYTES, stream);          // acc + T + mesh
    hipMemsetAsync(ws + COUNTS_OFF, 0, 4096, stream);     // tile counts
    table_kernel<<<(14400+255)/256, 256, 0, stream>>>(T);
    bin_count_q_kernel<<<gA, 256, 0, stream>>>(coords, box, charges, counts, acc, n);
    scan_kernel<<<1, 1024, 0, stream>>>(counts, offsets, cursor);
    scatter_kernel<<<gA, 256, 0, stream>>>(coords, box, charges, cursor, sorted, n);
    spread_tile_kernel<<<NTILE, 512, 0, stream>>>(sorted, offsets, mesh);
    fft_z_kernel<<<120*4, 256, 0, stream>>>(mesh, T, C1);
    fft_y_kernel<<<15*NKZ, 256, 0, stream>>>(C1, T, C2);
    fft_x_energy_kernel<<<NKZ*15, 256, 0, stream>>>(C2, T, box, acc);
    finalize_kernel<<<1, 1, 0, stream>>>(acc, box, (float*)d_out);
}